// Round 1
// baseline (567.041 us; speedup 1.0000x reference)
//
#include <hip/hip_runtime.h>
#include <math.h>

#define N_IMG 8
#define C_CH 19
#define H_IMG 512
#define W_IMG 1024
#define HW (H_IMG * W_IMG)          // 524288 = 2^19
#define HS 64
#define WSDS 128
#define NDS (N_IMG * HS * WSDS)     // 65536 downsampled pixels
#define K_TH 3124                   // min(65536, 200000/64) - 1
#define THRESH_F 0.6f

// ---------------------------------------------------------------------------
// K1: pred_s[idx] = bilinear interp (at 8x downsample coords) of softmax prob
// at the nearest-downsampled target label. One thread per downsampled pixel.
// Writes 65536 floats into scratch (front of d_out, overwritten later by K3).
// ---------------------------------------------------------------------------
__global__ __launch_bounds__(256) void k1_pred_s(const float* __restrict__ predict,
                                                 const int* __restrict__ target,
                                                 float* __restrict__ pred_s) {
    int idx = blockIdx.x * blockDim.x + threadIdx.x;
    if (idx >= NDS) return;
    int n = idx >> 13;          // / (64*128)
    int r = idx & 8191;
    int j = r >> 7;             // ds row
    int i = r & 127;            // ds col

    // scipy.ndimage.zoom coords: in = out * (n_in-1)/(n_out-1)
    float yc = (float)j * (511.0f / 63.0f);
    float xc = (float)i * (1023.0f / 127.0f);
    int y0 = (int)floorf(yc);
    if (y0 > H_IMG - 1) y0 = H_IMG - 1;
    int y1 = min(y0 + 1, H_IMG - 1);
    float wy = yc - (float)y0;
    int x0 = (int)floorf(xc);
    if (x0 > W_IMG - 1) x0 = W_IMG - 1;
    int x1 = min(x0 + 1, W_IMG - 1);
    float wx = xc - (float)x0;

    // nearest (round-half-even, matches jnp.round; no exact .5 cases exist)
    int yi = min((int)rintf(yc), H_IMG - 1);
    int xi = min((int)rintf(xc), W_IMG - 1);
    int L = target[n * HW + yi * W_IMG + xi];
    if (L < 0) L = 0;  // guard (labels are 0..18 here)

    const float* base = predict + (size_t)n * C_CH * HW;
    int offs[4] = { y0 * W_IMG + x0, y0 * W_IMG + x1,
                    y1 * W_IMG + x0, y1 * W_IMG + x1 };
    float p[4];
    for (int cr = 0; cr < 4; cr++) {
        const float* pp = base + offs[cr];
        float v[C_CH];
        float m = -INFINITY;
        #pragma unroll
        for (int c = 0; c < C_CH; c++) {
            float x = pp[(size_t)c * HW];
            v[c] = x;
            m = fmaxf(m, x);
        }
        float s = 0.0f, eL = 0.0f;
        #pragma unroll
        for (int c = 0; c < C_CH; c++) {
            float e = expf(v[c] - m);
            s += e;
            if (c == L) eL = e;
        }
        p[cr] = eL / s;
    }
    float a0 = p[0] * (1.0f - wy) + p[2] * wy;   // combine along y first (ref order)
    float a1 = p[1] * (1.0f - wy) + p[3] * wy;
    pred_s[idx] = a0 * (1.0f - wx) + a1 * wx;
}

// ---------------------------------------------------------------------------
// K2: exact k-th smallest of 65536 positive floats via 3-level radix select
// on the uint32 bit pattern (positive floats: uint order == float order).
// Single block, 1024 threads, LDS histograms. threshold = max(kth, 0.6).
// ---------------------------------------------------------------------------
__global__ __launch_bounds__(1024) void k2_select(const float* __restrict__ pred_s,
                                                  float* __restrict__ thr_out) {
    __shared__ unsigned int hist[2048];
    __shared__ unsigned int s_bin, s_k;
    int t = threadIdx.x;
    unsigned int prefix = 0;
    unsigned int k = K_TH;

    for (int lvl = 0; lvl < 3; lvl++) {
        int nb = (lvl == 2) ? 1024 : 2048;
        for (int b = t; b < nb; b += 1024) hist[b] = 0;
        __syncthreads();
        for (int idx = t; idx < NDS; idx += 1024) {
            unsigned int u = __float_as_uint(pred_s[idx]);
            bool ok;
            unsigned int bin;
            if (lvl == 0)      { ok = true;                bin = u >> 21; }
            else if (lvl == 1) { ok = (u >> 21) == prefix; bin = (u >> 10) & 2047u; }
            else               { ok = (u >> 10) == prefix; bin = u & 1023u; }
            if (ok) atomicAdd(&hist[bin], 1u);
        }
        __syncthreads();
        if (t == 0) {
            unsigned int cum = 0;
            for (int b = 0; b < nb; b++) {
                unsigned int c = hist[b];
                if (cum + c > k) { s_bin = (unsigned int)b; s_k = k - cum; break; }
                cum += c;
            }
        }
        __syncthreads();
        unsigned int b = s_bin;
        k = s_k;
        if (lvl == 0)      prefix = b;
        else if (lvl == 1) prefix = (prefix << 11) | b;
        else               prefix = (prefix << 10) | b;
        __syncthreads();
    }
    if (t == 0) {
        float kth = __uint_as_float(prefix);
        *thr_out = (kth > THRESH_F) ? kth : THRESH_F;
    }
}

// ---------------------------------------------------------------------------
// K3: full-resolution pass. Two-pass softmax (max then exp-sum) per pixel in
// f32 (matches jax f32 semantics), pred = exp(v[t]-m)/sum, keep if <= thr.
// One thread per 4 consecutive pixels (float4/int4 coalesced, 16 B/lane).
// ---------------------------------------------------------------------------
__global__ __launch_bounds__(256) void k3_final(const float* __restrict__ predict,
                                                const int* __restrict__ target,
                                                const float* __restrict__ thr_ptr,
                                                int* __restrict__ out) {
    int tid = blockIdx.x * blockDim.x + threadIdx.x;
    int p = tid * 4;
    if (p >= N_IMG * HW) return;
    int n = p >> 19;            // / HW
    int o = p & (HW - 1);
    const float* base = predict + (size_t)n * C_CH * HW + o;

    float4 v[C_CH];
    float4 m = make_float4(-INFINITY, -INFINITY, -INFINITY, -INFINITY);
    #pragma unroll
    for (int c = 0; c < C_CH; c++) {
        float4 x = *reinterpret_cast<const float4*>(base + (size_t)c * HW);
        v[c] = x;
        m.x = fmaxf(m.x, x.x); m.y = fmaxf(m.y, x.y);
        m.z = fmaxf(m.z, x.z); m.w = fmaxf(m.w, x.w);
    }
    int4 tg = *reinterpret_cast<const int4*>(target + p);
    float4 s = make_float4(0.f, 0.f, 0.f, 0.f);
    float4 et = make_float4(0.f, 0.f, 0.f, 0.f);
    #pragma unroll
    for (int c = 0; c < C_CH; c++) {
        float ex = expf(v[c].x - m.x);
        float ey = expf(v[c].y - m.y);
        float ez = expf(v[c].z - m.z);
        float ew = expf(v[c].w - m.w);
        s.x += ex; s.y += ey; s.z += ez; s.w += ew;
        if (c == tg.x) et.x = ex;
        if (c == tg.y) et.y = ey;
        if (c == tg.z) et.z = ez;
        if (c == tg.w) et.w = ew;
    }
    float thr = *thr_ptr;
    int4 r;
    r.x = ((et.x / s.x) <= thr && tg.x >= 0) ? tg.x : -1;
    r.y = ((et.y / s.y) <= thr && tg.y >= 0) ? tg.y : -1;
    r.z = ((et.z / s.z) <= thr && tg.z >= 0) ? tg.z : -1;
    r.w = ((et.w / s.w) <= thr && tg.w >= 0) ? tg.w : -1;
    *reinterpret_cast<int4*>(out + p) = r;
}

extern "C" void kernel_launch(void* const* d_in, const int* in_sizes, int n_in,
                              void* d_out, int out_size, void* d_ws, size_t ws_size,
                              hipStream_t stream) {
    const float* predict = (const float*)d_in[0];   // (8,19,512,1024) f32
    const int* target    = (const int*)d_in[1];     // (8,512,1024) i32
    int* out = (int*)d_out;

    // Scratch: pred_s lives in the front of d_out (256 KB of 16.8 MB); it is
    // consumed by K2 before K3 overwrites the whole buffer. Threshold in d_ws.
    float* pred_s = (float*)d_out;
    float* thr    = (float*)d_ws;

    hipLaunchKernelGGL(k1_pred_s, dim3(NDS / 256), dim3(256), 0, stream,
                       predict, target, pred_s);
    hipLaunchKernelGGL(k2_select, dim3(1), dim3(1024), 0, stream, pred_s, thr);
    hipLaunchKernelGGL(k3_final, dim3((N_IMG * HW) / (4 * 256)), dim3(256), 0, stream,
                       predict, target, thr, out);
}

// Round 2
// 492.109 us; speedup vs baseline: 1.1523x; 1.1523x over previous
//
#include <hip/hip_runtime.h>
#include <math.h>

#define N_IMG 8
#define C_CH 19
#define H_IMG 512
#define W_IMG 1024
#define HW (H_IMG * W_IMG)          // 524288 = 2^19
#define HS 64
#define WSDS 128
#define NDS (N_IMG * HS * WSDS)     // 65536 downsampled pixels
#define K_TH 3124                   // min(65536, 200000/64) - 1
#define THRESH_F 0.6f

// ---------------------------------------------------------------------------
// K1: pred_s[idx] = bilinear interp (at 8x downsample coords) of softmax prob
// at the nearest-downsampled target label. One thread per downsampled pixel.
// Writes 65536 floats into scratch (front of d_out, overwritten later by K3).
// ---------------------------------------------------------------------------
__global__ __launch_bounds__(256) void k1_pred_s(const float* __restrict__ predict,
                                                 const int* __restrict__ target,
                                                 float* __restrict__ pred_s) {
    int idx = blockIdx.x * blockDim.x + threadIdx.x;
    if (idx >= NDS) return;
    int n = idx >> 13;          // / (64*128)
    int r = idx & 8191;
    int j = r >> 7;             // ds row
    int i = r & 127;            // ds col

    // scipy.ndimage.zoom coords: in = out * (n_in-1)/(n_out-1)
    float yc = (float)j * (511.0f / 63.0f);
    float xc = (float)i * (1023.0f / 127.0f);
    int y0 = (int)floorf(yc);
    if (y0 > H_IMG - 1) y0 = H_IMG - 1;
    int y1 = min(y0 + 1, H_IMG - 1);
    float wy = yc - (float)y0;
    int x0 = (int)floorf(xc);
    if (x0 > W_IMG - 1) x0 = W_IMG - 1;
    int x1 = min(x0 + 1, W_IMG - 1);
    float wx = xc - (float)x0;

    // nearest (round-half-even, matches jnp.round; no exact .5 cases exist)
    int yi = min((int)rintf(yc), H_IMG - 1);
    int xi = min((int)rintf(xc), W_IMG - 1);
    int L = target[n * HW + yi * W_IMG + xi];
    if (L < 0) L = 0;  // guard (labels are 0..18 here)

    const float* base = predict + (size_t)n * C_CH * HW;
    int offs[4] = { y0 * W_IMG + x0, y0 * W_IMG + x1,
                    y1 * W_IMG + x0, y1 * W_IMG + x1 };
    float p[4];
    for (int cr = 0; cr < 4; cr++) {
        const float* pp = base + offs[cr];
        float v[C_CH];
        float m = -INFINITY;
        #pragma unroll
        for (int c = 0; c < C_CH; c++) {
            float x = pp[(size_t)c * HW];
            v[c] = x;
            m = fmaxf(m, x);
        }
        float s = 0.0f, eL = 0.0f;
        #pragma unroll
        for (int c = 0; c < C_CH; c++) {
            float e = expf(v[c] - m);
            s += e;
            if (c == L) eL = e;
        }
        p[cr] = eL / s;
    }
    float a0 = p[0] * (1.0f - wy) + p[2] * wy;   // combine along y first (ref order)
    float a1 = p[1] * (1.0f - wy) + p[3] * wy;
    pred_s[idx] = a0 * (1.0f - wx) + a1 * wx;
}

// ---------------------------------------------------------------------------
// K2 v2: exact k-th smallest of 65536 positive floats, 3-level radix select
// on the uint32 bit pattern (positive floats: uint order == float order).
// Single block, 1024 threads (16 waves).
//   - per-WAVE privatized histograms (16 x 2048 bins = 128 KB LDS) so LDS
//     atomic contention is wave-local, parallel across waves
//   - parallel rank search: wave shuffle-scan + wave-offset sum instead of
//     a thread-0 serial walk (was ~5120 dependent ds_reads ~ 250 us)
//   - re-reads pred_s (256 KB, L2-hot) each level to keep VGPR <= 128 so the
//     1024-thread block launches at full occupancy
// ---------------------------------------------------------------------------
#define K2_THREADS 1024
#define K2_WAVES (K2_THREADS / 64)

__global__ __launch_bounds__(K2_THREADS) void k2_select(const float* __restrict__ pred_s,
                                                        float* __restrict__ thr_out) {
    __shared__ unsigned int hist[K2_WAVES * 2048];   // 128 KB
    __shared__ unsigned int tot[2048];               // 8 KB
    __shared__ unsigned int wsum[K2_WAVES];
    __shared__ unsigned int s_bin, s_k;

    const int t = threadIdx.x;
    const int lane = t & 63;
    const int wave = t >> 6;

    unsigned int prefix = 0;
    unsigned int k = K_TH;

    for (int lvl = 0; lvl < 3; lvl++) {
        const int nb = (lvl == 2) ? 1024 : 2048;

        // zero my waves' histogram slice
        for (int b = t; b < K2_WAVES * nb; b += K2_THREADS) hist[b] = 0;
        __syncthreads();

        // accumulate into per-wave histogram
        unsigned int* myhist = &hist[wave * nb];
        for (int idx = t; idx < NDS; idx += K2_THREADS) {
            unsigned int u = __float_as_uint(pred_s[idx]);
            bool ok;
            unsigned int bin;
            if (lvl == 0)      { ok = true;                bin = u >> 21; }
            else if (lvl == 1) { ok = (u >> 21) == prefix; bin = (u >> 10) & 2047u; }
            else               { ok = (u >> 10) == prefix; bin = u & 1023u; }
            if (ok) atomicAdd(&myhist[bin], 1u);
        }
        __syncthreads();

        // reduce 16 wave-histograms -> tot[b]
        for (int b = t; b < nb; b += K2_THREADS) {
            unsigned int s = 0;
            #pragma unroll
            for (int w = 0; w < K2_WAVES; w++) s += hist[w * nb + b];
            tot[b] = s;
        }
        __syncthreads();

        // parallel rank search: each thread owns nb/1024 consecutive bins
        unsigned int c0, c1, s;
        if (nb == 2048) { c0 = tot[2 * t]; c1 = tot[2 * t + 1]; s = c0 + c1; }
        else            { c0 = tot[t];     c1 = 0;              s = c0; }

        unsigned int incl = s;
        #pragma unroll
        for (int off = 1; off < 64; off <<= 1) {
            unsigned int v = (unsigned int)__shfl_up((int)incl, off, 64);
            if (lane >= off) incl += v;
        }
        if (lane == 63) wsum[wave] = incl;
        __syncthreads();
        unsigned int woff = 0;
        for (int w = 0; w < wave; w++) woff += wsum[w];
        unsigned int excl = woff + incl - s;   // exclusive prefix of my chunk

        if (k >= excl && k < excl + s) {       // unique owner of rank k
            if (nb == 2048) {
                if (k < excl + c0) { s_bin = 2u * t;     s_k = k - excl; }
                else               { s_bin = 2u * t + 1; s_k = k - excl - c0; }
            } else {
                s_bin = (unsigned int)t; s_k = k - excl;
            }
        }
        __syncthreads();

        unsigned int b = s_bin;
        k = s_k;
        if (lvl == 0)      prefix = b;
        else if (lvl == 1) prefix = (prefix << 11) | b;
        else               prefix = (prefix << 10) | b;
        __syncthreads();
    }

    if (t == 0) {
        float kth = __uint_as_float(prefix);
        *thr_out = (kth > THRESH_F) ? kth : THRESH_F;
    }
}

// ---------------------------------------------------------------------------
// K3: full-resolution pass. Two-pass softmax (max then exp-sum) per pixel in
// f32 (matches jax f32 semantics), pred = exp(v[t]-m)/sum, keep if <= thr.
// One thread per 4 consecutive pixels (float4/int4 coalesced, 16 B/lane).
// ---------------------------------------------------------------------------
__global__ __launch_bounds__(256) void k3_final(const float* __restrict__ predict,
                                                const int* __restrict__ target,
                                                const float* __restrict__ thr_ptr,
                                                int* __restrict__ out) {
    int tid = blockIdx.x * blockDim.x + threadIdx.x;
    int p = tid * 4;
    if (p >= N_IMG * HW) return;
    int n = p >> 19;            // / HW
    int o = p & (HW - 1);
    const float* base = predict + (size_t)n * C_CH * HW + o;

    float4 v[C_CH];
    float4 m = make_float4(-INFINITY, -INFINITY, -INFINITY, -INFINITY);
    #pragma unroll
    for (int c = 0; c < C_CH; c++) {
        float4 x = *reinterpret_cast<const float4*>(base + (size_t)c * HW);
        v[c] = x;
        m.x = fmaxf(m.x, x.x); m.y = fmaxf(m.y, x.y);
        m.z = fmaxf(m.z, x.z); m.w = fmaxf(m.w, x.w);
    }
    int4 tg = *reinterpret_cast<const int4*>(target + p);
    float4 s = make_float4(0.f, 0.f, 0.f, 0.f);
    float4 et = make_float4(0.f, 0.f, 0.f, 0.f);
    #pragma unroll
    for (int c = 0; c < C_CH; c++) {
        float ex = expf(v[c].x - m.x);
        float ey = expf(v[c].y - m.y);
        float ez = expf(v[c].z - m.z);
        float ew = expf(v[c].w - m.w);
        s.x += ex; s.y += ey; s.z += ez; s.w += ew;
        if (c == tg.x) et.x = ex;
        if (c == tg.y) et.y = ey;
        if (c == tg.z) et.z = ez;
        if (c == tg.w) et.w = ew;
    }
    float thr = *thr_ptr;
    int4 r;
    r.x = ((et.x / s.x) <= thr && tg.x >= 0) ? tg.x : -1;
    r.y = ((et.y / s.y) <= thr && tg.y >= 0) ? tg.y : -1;
    r.z = ((et.z / s.z) <= thr && tg.z >= 0) ? tg.z : -1;
    r.w = ((et.w / s.w) <= thr && tg.w >= 0) ? tg.w : -1;
    *reinterpret_cast<int4*>(out + p) = r;
}

extern "C" void kernel_launch(void* const* d_in, const int* in_sizes, int n_in,
                              void* d_out, int out_size, void* d_ws, size_t ws_size,
                              hipStream_t stream) {
    const float* predict = (const float*)d_in[0];   // (8,19,512,1024) f32
    const int* target    = (const int*)d_in[1];     // (8,512,1024) i32
    int* out = (int*)d_out;

    // Scratch: pred_s lives in the front of d_out (256 KB of 16.8 MB); it is
    // consumed by K2 before K3 overwrites the whole buffer. Threshold in d_ws.
    float* pred_s = (float*)d_out;
    float* thr    = (float*)d_ws;

    hipLaunchKernelGGL(k1_pred_s, dim3(NDS / 256), dim3(256), 0, stream,
                       predict, target, pred_s);
    hipLaunchKernelGGL(k2_select, dim3(1), dim3(K2_THREADS), 0, stream, pred_s, thr);
    hipLaunchKernelGGL(k3_final, dim3((N_IMG * HW) / (4 * 256)), dim3(256), 0, stream,
                       predict, target, thr, out);
}

// Round 4
// 474.400 us; speedup vs baseline: 1.1953x; 1.0373x over previous
//
#include <hip/hip_runtime.h>
#include <math.h>

#define N_IMG 8
#define C_CH 19
#define H_IMG 512
#define W_IMG 1024
#define HW (H_IMG * W_IMG)          // 524288 = 2^19
#define HS 64
#define WSDS 128
#define NDS (N_IMG * HS * WSDS)     // 65536 downsampled pixels
#define K_TH 3124                   // min(65536, 200000/64) - 1
#define THRESH_F 0.6f

// native clang vector types (HIP_vector_type structs are rejected by
// __builtin_nontemporal_load/store)
typedef float  f32x4 __attribute__((ext_vector_type(4)));
typedef int    i32x4 __attribute__((ext_vector_type(4)));

// ---------------------------------------------------------------------------
// K1 v3: one thread per (ds-pixel, corner). 262144 threads, 1024 blocks ->
// ~4 blocks/CU (v2 had 1 wave/SIMD: zero latency hiding).
// Each thread computes softmax prob at label L for its corner, scales by its
// bilinear weight, then the 4 corner lanes (adjacent in the wave) sum via
// shfl_xor. Summation-order differs from ref by ulps (~0.01 magnitude) which
// cannot move the threshold (clamped at 0.6) -> output unaffected.
// ---------------------------------------------------------------------------
__global__ __launch_bounds__(256) void k1_pred_s(const float* __restrict__ predict,
                                                 const int* __restrict__ target,
                                                 float* __restrict__ pred_s) {
    int t = threadIdx.x;
    int g = blockIdx.x * 64 + (t >> 2);   // ds-pixel index 0..65535
    int cr = t & 3;                        // corner: bit0 = x-side, bit1 = y-side
    int n = g >> 13;
    int r = g & 8191;
    int j = r >> 7;             // ds row
    int i = r & 127;            // ds col

    // scipy.ndimage.zoom coords: in = out * (n_in-1)/(n_out-1)
    float yc = (float)j * (511.0f / 63.0f);
    float xc = (float)i * (1023.0f / 127.0f);
    int y0 = (int)floorf(yc);
    if (y0 > H_IMG - 1) y0 = H_IMG - 1;
    int y1 = min(y0 + 1, H_IMG - 1);
    float wy = yc - (float)y0;
    int x0 = (int)floorf(xc);
    if (x0 > W_IMG - 1) x0 = W_IMG - 1;
    int x1 = min(x0 + 1, W_IMG - 1);
    float wx = xc - (float)x0;

    // nearest-neighbor label (round-half-even; no exact .5 cases here)
    int yi = min((int)rintf(yc), H_IMG - 1);
    int xi = min((int)rintf(xc), W_IMG - 1);
    int L = target[n * HW + yi * W_IMG + xi];
    if (L < 0) L = 0;

    int yy = (cr & 2) ? y1 : y0;
    int xx = (cr & 1) ? x1 : x0;
    float w = ((cr & 2) ? wy : 1.0f - wy) * ((cr & 1) ? wx : 1.0f - wx);

    const float* pp = predict + (size_t)n * C_CH * HW + yy * W_IMG + xx;
    float v[C_CH];
    float m = -INFINITY;
    #pragma unroll
    for (int c = 0; c < C_CH; c++) {
        float x = pp[(size_t)c * HW];
        v[c] = x;
        m = fmaxf(m, x);
    }
    float s = 0.0f, eL = 0.0f;
    #pragma unroll
    for (int c = 0; c < C_CH; c++) {
        float e = expf(v[c] - m);
        s += e;
        if (c == L) eL = e;
    }
    float p = w * (eL / s);

    // sum the 4 corner lanes (t, t^1, t^2, t^3 all within one wave since 4|64)
    p += __shfl_xor(p, 1, 64);
    p += __shfl_xor(p, 2, 64);
    if (cr == 0) pred_s[g] = p;
}

// ---------------------------------------------------------------------------
// K2: exact k-th smallest of 65536 positive floats, 3-level radix select
// (11+11+10 bits) on the uint32 bit pattern (positive floats: uint order ==
// float order). Single block, 1024 threads (16 waves).
//   - per-WAVE privatized histograms (16 x 2048 bins = 128 KB LDS)
//   - parallel rank search: wave shuffle-scan + wave-offset sum
// ---------------------------------------------------------------------------
#define K2_THREADS 1024
#define K2_WAVES (K2_THREADS / 64)

__global__ __launch_bounds__(K2_THREADS) void k2_select(const float* __restrict__ pred_s,
                                                        float* __restrict__ thr_out) {
    __shared__ unsigned int hist[K2_WAVES * 2048];   // 128 KB
    __shared__ unsigned int tot[2048];               // 8 KB
    __shared__ unsigned int wsum[K2_WAVES];
    __shared__ unsigned int s_bin, s_k;

    const int t = threadIdx.x;
    const int lane = t & 63;
    const int wave = t >> 6;

    unsigned int prefix = 0;
    unsigned int k = K_TH;

    for (int lvl = 0; lvl < 3; lvl++) {
        const int nb = (lvl == 2) ? 1024 : 2048;

        for (int b = t; b < K2_WAVES * nb; b += K2_THREADS) hist[b] = 0;
        __syncthreads();

        unsigned int* myhist = &hist[wave * nb];
        for (int idx = t; idx < NDS; idx += K2_THREADS) {
            unsigned int u = __float_as_uint(pred_s[idx]);
            bool ok;
            unsigned int bin;
            if (lvl == 0)      { ok = true;                bin = u >> 21; }
            else if (lvl == 1) { ok = (u >> 21) == prefix; bin = (u >> 10) & 2047u; }
            else               { ok = (u >> 10) == prefix; bin = u & 1023u; }
            if (ok) atomicAdd(&myhist[bin], 1u);
        }
        __syncthreads();

        for (int b = t; b < nb; b += K2_THREADS) {
            unsigned int s = 0;
            #pragma unroll
            for (int w = 0; w < K2_WAVES; w++) s += hist[w * nb + b];
            tot[b] = s;
        }
        __syncthreads();

        unsigned int c0, c1, s;
        if (nb == 2048) { c0 = tot[2 * t]; c1 = tot[2 * t + 1]; s = c0 + c1; }
        else            { c0 = tot[t];     c1 = 0;              s = c0; }

        unsigned int incl = s;
        #pragma unroll
        for (int off = 1; off < 64; off <<= 1) {
            unsigned int v = (unsigned int)__shfl_up((int)incl, off, 64);
            if (lane >= off) incl += v;
        }
        if (lane == 63) wsum[wave] = incl;
        __syncthreads();
        unsigned int woff = 0;
        for (int w = 0; w < wave; w++) woff += wsum[w];
        unsigned int excl = woff + incl - s;   // exclusive prefix of my chunk

        if (k >= excl && k < excl + s) {       // unique owner of rank k
            if (nb == 2048) {
                if (k < excl + c0) { s_bin = 2u * t;     s_k = k - excl; }
                else               { s_bin = 2u * t + 1; s_k = k - excl - c0; }
            } else {
                s_bin = (unsigned int)t; s_k = k - excl;
            }
        }
        __syncthreads();

        unsigned int b = s_bin;
        k = s_k;
        if (lvl == 0)      prefix = b;
        else if (lvl == 1) prefix = (prefix << 11) | b;
        else               prefix = (prefix << 10) | b;
        __syncthreads();
    }

    if (t == 0) {
        float kth = __uint_as_float(prefix);
        *thr_out = (kth > THRESH_F) ? kth : THRESH_F;
    }
}

// ---------------------------------------------------------------------------
// K3: full-resolution pass. Two-pass softmax (max then exp-sum) per pixel in
// f32 (matches jax f32 semantics), pred = exp(v[t]-m)/sum, keep if <= thr.
// One thread per 4 consecutive pixels. Nontemporal loads on the 318 MB
// predict stream (no reuse; keep L2 for target/out).
// ---------------------------------------------------------------------------
__global__ __launch_bounds__(256) void k3_final(const float* __restrict__ predict,
                                                const int* __restrict__ target,
                                                const float* __restrict__ thr_ptr,
                                                int* __restrict__ out) {
    int tid = blockIdx.x * blockDim.x + threadIdx.x;
    int p = tid * 4;
    if (p >= N_IMG * HW) return;
    int n = p >> 19;            // / HW
    int o = p & (HW - 1);
    const float* base = predict + (size_t)n * C_CH * HW + o;

    i32x4 tg = *reinterpret_cast<const i32x4*>(target + p);

    f32x4 v[C_CH];
    f32x4 m = (f32x4)(-INFINITY);
    #pragma unroll
    for (int c = 0; c < C_CH; c++) {
        f32x4 x = __builtin_nontemporal_load(
            reinterpret_cast<const f32x4*>(base + (size_t)c * HW));
        v[c] = x;
        m.x = fmaxf(m.x, x.x); m.y = fmaxf(m.y, x.y);
        m.z = fmaxf(m.z, x.z); m.w = fmaxf(m.w, x.w);
    }
    f32x4 s = (f32x4)(0.0f);
    f32x4 et = (f32x4)(0.0f);
    #pragma unroll
    for (int c = 0; c < C_CH; c++) {
        float ex = expf(v[c].x - m.x);
        float ey = expf(v[c].y - m.y);
        float ez = expf(v[c].z - m.z);
        float ew = expf(v[c].w - m.w);
        s.x += ex; s.y += ey; s.z += ez; s.w += ew;
        if (c == tg.x) et.x = ex;
        if (c == tg.y) et.y = ey;
        if (c == tg.z) et.z = ez;
        if (c == tg.w) et.w = ew;
    }
    float thr = *thr_ptr;
    i32x4 r;
    r.x = ((et.x / s.x) <= thr && tg.x >= 0) ? tg.x : -1;
    r.y = ((et.y / s.y) <= thr && tg.y >= 0) ? tg.y : -1;
    r.z = ((et.z / s.z) <= thr && tg.z >= 0) ? tg.z : -1;
    r.w = ((et.w / s.w) <= thr && tg.w >= 0) ? tg.w : -1;
    __builtin_nontemporal_store(r, reinterpret_cast<i32x4*>(out + p));
}

extern "C" void kernel_launch(void* const* d_in, const int* in_sizes, int n_in,
                              void* d_out, int out_size, void* d_ws, size_t ws_size,
                              hipStream_t stream) {
    const float* predict = (const float*)d_in[0];   // (8,19,512,1024) f32
    const int* target    = (const int*)d_in[1];     // (8,512,1024) i32
    int* out = (int*)d_out;

    // Scratch: pred_s lives in the front of d_out (256 KB of 16.8 MB); it is
    // consumed by K2 before K3 overwrites the whole buffer. Threshold in d_ws.
    float* pred_s = (float*)d_out;
    float* thr    = (float*)d_ws;

    hipLaunchKernelGGL(k1_pred_s, dim3(NDS * 4 / 256), dim3(256), 0, stream,
                       predict, target, pred_s);
    hipLaunchKernelGGL(k2_select, dim3(1), dim3(K2_THREADS), 0, stream, pred_s, thr);
    hipLaunchKernelGGL(k3_final, dim3((N_IMG * HW) / (4 * 256)), dim3(256), 0, stream,
                       predict, target, thr, out);
}

// Round 5
// 471.607 us; speedup vs baseline: 1.2024x; 1.0059x over previous
//
#include <hip/hip_runtime.h>
#include <math.h>

#define N_IMG 8
#define C_CH 19
#define H_IMG 512
#define W_IMG 1024
#define HW (H_IMG * W_IMG)          // 524288 = 2^19
#define NDS (N_IMG * 64 * 128)      // 65536 downsampled pixels
#define K_TH 3124                   // min(65536, 200000/64) - 1
#define THRESH_F 0.6f

typedef float  f32x4 __attribute__((ext_vector_type(4)));
typedef int    i32x4 __attribute__((ext_vector_type(4)));

// ---------------------------------------------------------------------------
// K0: zero the pred_s accumulator (d_ws is poisoned 0xAA before every call).
// ---------------------------------------------------------------------------
__global__ __launch_bounds__(256) void k0_zero(float* __restrict__ pred_s) {
    int idx = (blockIdx.x * 256 + threadIdx.x) * 4;
    *reinterpret_cast<f32x4*>(pred_s + idx) = (f32x4)(0.0f);
}

// ---------------------------------------------------------------------------
// K1 fused: single streaming pass over predict (318 MB, read ONCE).
//  - per-pixel softmax (two-pass max/exp-sum, f32, matches jax semantics)
//  - writes pred_full = prob at own target (16.8 MB, consumed by K3)
//  - pixels that are bilinear-downsample corners (6.25%) scatter their
//    weighted prob-at-ds-label into pred_s via global atomicAdd.
// FP note: corner summation order differs from ref by ulps at ~0.01
// magnitude; the threshold clamp at 0.6 makes the final output identical.
// ---------------------------------------------------------------------------
__global__ __launch_bounds__(256) void k1_fused(const float* __restrict__ predict,
                                                const int* __restrict__ target,
                                                float* __restrict__ pred_full,
                                                float* __restrict__ pred_s) {
    int tid = blockIdx.x * blockDim.x + threadIdx.x;
    int p = tid * 4;
    int n = p >> 19;            // / HW
    int o = p & (HW - 1);
    int y = o >> 10;            // row (W=1024)
    int xb = o & 1023;          // base col of this 4-pixel quad
    const float* base = predict + (size_t)n * C_CH * HW + o;

    i32x4 tg = *reinterpret_cast<const i32x4*>(target + p);

    f32x4 v[C_CH];
    f32x4 m = (f32x4)(-INFINITY);
    #pragma unroll
    for (int c = 0; c < C_CH; c++) {
        f32x4 x = __builtin_nontemporal_load(
            reinterpret_cast<const f32x4*>(base + (size_t)c * HW));
        v[c] = x;
        m.x = fmaxf(m.x, x.x); m.y = fmaxf(m.y, x.y);
        m.z = fmaxf(m.z, x.z); m.w = fmaxf(m.w, x.w);
    }
    f32x4 s = (f32x4)(0.0f);
    f32x4 et = (f32x4)(0.0f);
    #pragma unroll
    for (int c = 0; c < C_CH; c++) {
        float ex = expf(v[c].x - m.x);
        float ey = expf(v[c].y - m.y);
        float ez = expf(v[c].z - m.z);
        float ew = expf(v[c].w - m.w);
        s.x += ex; s.y += ey; s.z += ez; s.w += ew;
        if (c == tg.x) et.x = ex;
        if (c == tg.y) et.y = ey;
        if (c == tg.z) et.z = ez;
        if (c == tg.w) et.w = ew;
    }
    f32x4 pf;
    pf.x = et.x / s.x; pf.y = et.y / s.y; pf.z = et.z / s.z; pf.w = et.w / s.w;
    *reinterpret_cast<f32x4*>(pred_full + p) = pf;   // regular store: L2/L3-hot for K3

    // ---- corner scatter (cold path) ----
    // y-matches: ds-rows j whose y0 or y1 equals this row (<=2, usually 0/1)
    int jm[2]; float wym[2]; int yrow[2]; int nym = 0;
    {
        int jc = (int)((float)y * (63.0f / 511.0f));
        for (int dj = -1; dj <= 2; dj++) {
            int j = jc + dj;
            if (j < 0 || j > 63) continue;
            float yc = (float)j * (511.0f / 63.0f);
            int y0 = (int)yc;
            if (y0 > H_IMG - 1) y0 = H_IMG - 1;
            int y1 = min(y0 + 1, H_IMG - 1);
            float wy = yc - (float)y0;
            int yi = min((int)rintf(yc), H_IMG - 1);
            if (y0 == y && nym < 2) { jm[nym] = j; wym[nym] = 1.0f - wy; yrow[nym] = yi; nym++; }
            if (y1 == y && nym < 2) { jm[nym] = j; wym[nym] = wy;        yrow[nym] = yi; nym++; }
        }
    }
    if (nym) {
        #pragma unroll
        for (int k = 0; k < 4; k++) {
            int x = xb + k;
            int im[2]; float wxm[2]; int xcol[2]; int nxm = 0;
            int ic = (int)((float)x * (127.0f / 1023.0f));
            for (int di = -1; di <= 2; di++) {
                int i = ic + di;
                if (i < 0 || i > 127) continue;
                float xc = (float)i * (1023.0f / 127.0f);
                int x0 = (int)xc;
                if (x0 > W_IMG - 1) x0 = W_IMG - 1;
                int x1 = min(x0 + 1, W_IMG - 1);
                float wx = xc - (float)x0;
                int xi = min((int)rintf(xc), W_IMG - 1);
                if (x0 == x && nxm < 2) { im[nxm] = i; wxm[nxm] = 1.0f - wx; xcol[nxm] = xi; nxm++; }
                if (x1 == x && nxm < 2) { im[nxm] = i; wxm[nxm] = wx;        xcol[nxm] = xi; nxm++; }
            }
            for (int a = 0; a < nym; a++) {
                for (int b = 0; b < nxm; b++) {
                    int L = target[n * HW + yrow[a] * W_IMG + xcol[b]];
                    if (L < 0) L = 0;
                    float vL = v[0][k];
                    #pragma unroll
                    for (int c = 1; c < C_CH; c++) if (c == L) vL = v[c][k];
                    float e = expf(vL - m[k]);
                    float contrib = wym[a] * wxm[b] * (e / s[k]);
                    atomicAdd(&pred_s[n * 8192 + jm[a] * 128 + im[b]], contrib);
                }
            }
        }
    }
}

// ---------------------------------------------------------------------------
// K2: exact k-th smallest of 65536 positive floats, 3-level radix select
// (11+11+10 bits) on the uint32 bit pattern (positive floats: uint order ==
// float order). Single block, 1024 threads (16 waves).
//   - per-WAVE privatized histograms (16 x 2048 bins = 128 KB LDS)
//   - parallel rank search: wave shuffle-scan + wave-offset sum
// ---------------------------------------------------------------------------
#define K2_THREADS 1024
#define K2_WAVES (K2_THREADS / 64)

__global__ __launch_bounds__(K2_THREADS) void k2_select(const float* __restrict__ pred_s,
                                                        float* __restrict__ thr_out) {
    __shared__ unsigned int hist[K2_WAVES * 2048];   // 128 KB
    __shared__ unsigned int tot[2048];               // 8 KB
    __shared__ unsigned int wsum[K2_WAVES];
    __shared__ unsigned int s_bin, s_k;

    const int t = threadIdx.x;
    const int lane = t & 63;
    const int wave = t >> 6;

    unsigned int prefix = 0;
    unsigned int k = K_TH;

    for (int lvl = 0; lvl < 3; lvl++) {
        const int nb = (lvl == 2) ? 1024 : 2048;

        for (int b = t; b < K2_WAVES * nb; b += K2_THREADS) hist[b] = 0;
        __syncthreads();

        unsigned int* myhist = &hist[wave * nb];
        for (int idx = t; idx < NDS; idx += K2_THREADS) {
            unsigned int u = __float_as_uint(pred_s[idx]);
            bool ok;
            unsigned int bin;
            if (lvl == 0)      { ok = true;                bin = u >> 21; }
            else if (lvl == 1) { ok = (u >> 21) == prefix; bin = (u >> 10) & 2047u; }
            else               { ok = (u >> 10) == prefix; bin = u & 1023u; }
            if (ok) atomicAdd(&myhist[bin], 1u);
        }
        __syncthreads();

        for (int b = t; b < nb; b += K2_THREADS) {
            unsigned int sm = 0;
            #pragma unroll
            for (int w = 0; w < K2_WAVES; w++) sm += hist[w * nb + b];
            tot[b] = sm;
        }
        __syncthreads();

        unsigned int c0, c1, s;
        if (nb == 2048) { c0 = tot[2 * t]; c1 = tot[2 * t + 1]; s = c0 + c1; }
        else            { c0 = tot[t];     c1 = 0;              s = c0; }

        unsigned int incl = s;
        #pragma unroll
        for (int off = 1; off < 64; off <<= 1) {
            unsigned int vv = (unsigned int)__shfl_up((int)incl, off, 64);
            if (lane >= off) incl += vv;
        }
        if (lane == 63) wsum[wave] = incl;
        __syncthreads();
        unsigned int woff = 0;
        for (int w = 0; w < wave; w++) woff += wsum[w];
        unsigned int excl = woff + incl - s;   // exclusive prefix of my chunk

        if (k >= excl && k < excl + s) {       // unique owner of rank k
            if (nb == 2048) {
                if (k < excl + c0) { s_bin = 2u * t;     s_k = k - excl; }
                else               { s_bin = 2u * t + 1; s_k = k - excl - c0; }
            } else {
                s_bin = (unsigned int)t; s_k = k - excl;
            }
        }
        __syncthreads();

        unsigned int b = s_bin;
        k = s_k;
        if (lvl == 0)      prefix = b;
        else if (lvl == 1) prefix = (prefix << 11) | b;
        else               prefix = (prefix << 10) | b;
        __syncthreads();
    }

    if (t == 0) {
        float kth = __uint_as_float(prefix);
        *thr_out = (kth > THRESH_F) ? kth : THRESH_F;
    }
}

// ---------------------------------------------------------------------------
// K3: light mask pass. pred_full + target (50 MB, mostly L2/L3-hot) -> out.
// ---------------------------------------------------------------------------
__global__ __launch_bounds__(256) void k3_mask(const float* __restrict__ pred_full,
                                               const int* __restrict__ target,
                                               const float* __restrict__ thr_ptr,
                                               int* __restrict__ out) {
    int tid = blockIdx.x * blockDim.x + threadIdx.x;
    int p = tid * 4;
    f32x4 pf = *reinterpret_cast<const f32x4*>(pred_full + p);
    i32x4 tg = *reinterpret_cast<const i32x4*>(target + p);
    float thr = *thr_ptr;
    i32x4 r;
    r.x = (pf.x <= thr && tg.x >= 0) ? tg.x : -1;
    r.y = (pf.y <= thr && tg.y >= 0) ? tg.y : -1;
    r.z = (pf.z <= thr && tg.z >= 0) ? tg.z : -1;
    r.w = (pf.w <= thr && tg.w >= 0) ? tg.w : -1;
    __builtin_nontemporal_store(r, reinterpret_cast<i32x4*>(out + p));
}

extern "C" void kernel_launch(void* const* d_in, const int* in_sizes, int n_in,
                              void* d_out, int out_size, void* d_ws, size_t ws_size,
                              hipStream_t stream) {
    const float* predict = (const float*)d_in[0];   // (8,19,512,1024) f32
    const int* target    = (const int*)d_in[1];     // (8,512,1024) i32
    int* out = (int*)d_out;

    // d_ws layout: [0] threshold (4 B) | [4096] pred_s (256 KB) | [1 MB] pred_full (16.8 MB)
    float* thr       = (float*)d_ws;
    float* pred_s    = (float*)((char*)d_ws + 4096);
    float* pred_full = (float*)((char*)d_ws + (1 << 20));

    hipLaunchKernelGGL(k0_zero, dim3(NDS / (256 * 4)), dim3(256), 0, stream, pred_s);
    hipLaunchKernelGGL(k1_fused, dim3(N_IMG * HW / (4 * 256)), dim3(256), 0, stream,
                       predict, target, pred_full, pred_s);
    hipLaunchKernelGGL(k2_select, dim3(1), dim3(K2_THREADS), 0, stream, pred_s, thr);
    hipLaunchKernelGGL(k3_mask, dim3(N_IMG * HW / (4 * 256)), dim3(256), 0, stream,
                       pred_full, target, thr, out);
}